// Round 5
// baseline (241.579 us; speedup 1.0000x reference)
//
#include <hip/hip_runtime.h>
#include <hip/hip_bf16.h>

// SpectralConv2d (FNO): B=8, C_IN=C_OUT=32, H=W=256, modes 32x32 (low kx) + 32x32 (high kx), ky 0..31.
// rFFT(w) bf16-MFMA GEMM -> FFT(h) fp32 recurrence (ky-slice 4, h-split 4, LDS reduce)
// -> complex mix (weights read direct, Z in [mk][bi]) -> iFFT(h) fp32 recurrence (ky-slice 4)
// -> irFFT(w)+bias bf16-MFMA GEMM. Twiddle B-matrices read directly from global (L1-resident).

#define BD 256

typedef __attribute__((ext_vector_type(8))) short bf16x8;
typedef __attribute__((ext_vector_type(4))) float f32x4;

__device__ inline unsigned short f2bf(float f) {
    union { float f; unsigned u; } v; v.f = f;
    unsigned r = v.u + 0x7FFF + ((v.u >> 16) & 1);   // RNE
    return (unsigned short)(r >> 16);
}

// Setup: block 0 -> tw[t]=(cos,sin)(2pi t/256); blocks 1..128 -> BmA/BmC.
// BmA[n][w] (n=2ky+c): c=0 -> cos(2pi ky w/256), c=1 -> -sin    [64][256]
// BmC[w][k] (k=2ky+c): c=0 -> cos, c=1 -> -sin                  [256][64]
__global__ void k_setup(float2* __restrict__ tw,
                        unsigned short* __restrict__ BmA, unsigned short* __restrict__ BmC) {
    int b = blockIdx.x, t = threadIdx.x;
    if (b == 0) {
        double th = 6.283185307179586476925286766559 * (double)t / 256.0;
        tw[t] = make_float2((float)cos(th), (float)sin(th));
    } else {
        int idx = (b - 1) * BD + t;    // 0..32767
        if (idx < 16384) {
            int w = idx & 255, n = idx >> 8;
            int ky = n >> 1, c = n & 1;
            double th = 6.283185307179586476925286766559 * (double)((ky * w) & 255) / 256.0;
            BmA[idx] = f2bf(c ? (float)(-sin(th)) : (float)cos(th));
        } else {
            int j = idx - 16384;
            int k = j & 63, w = j >> 6;
            int ky = k >> 1, c = k & 1;
            double th = 6.283185307179586476925286766559 * (double)((ky * w) & 255) / 256.0;
            BmC[j] = f2bf(c ? (float)(-sin(th)) : (float)cos(th));
        }
    }
}

// A1 (MFMA): Y[row][n] = sum_w x[row][w] * BmA[n][w].  M-tile=32 rows, N=64, K=256.
// B fragments straight from global (32 KB, L1-resident).
__global__ void k_dft_w_mfma(const float* __restrict__ x, const unsigned short* __restrict__ BmA,
                             float* __restrict__ Y) {
    __shared__ unsigned short As[32 * 264];   // 32 rows x 256 bf16, k-stride 264
    int t = threadIdx.x;
    const float4* xb = (const float4*)(x + (long)blockIdx.x * 32 * 256);
#pragma unroll
    for (int k = 0; k < 8; ++k) {             // coalesced: thread-linear float4
        int j = k * BD + t;
        float4 v = xb[j];
        ushort4 bq;
        bq.x = f2bf(v.x); bq.y = f2bf(v.y); bq.z = f2bf(v.z); bq.w = f2bf(v.w);
        *(ushort4*)&As[(j >> 6) * 264 + (j & 63) * 4] = bq;
    }
    __syncthreads();
    int wv = t >> 6, lane = t & 63;
    int m = lane & 15, quad = lane >> 4;
    int rows16 = (wv >> 1) * 16;
    int ntb = (wv & 1) * 2;
    f32x4 acc[2] = {};
#pragma unroll
    for (int kk = 0; kk < 8; ++kk) {
        bf16x8 af = *(const bf16x8*)&As[(rows16 + m) * 264 + kk * 32 + quad * 8];
#pragma unroll
        for (int j = 0; j < 2; ++j) {
            bf16x8 bf = *(const bf16x8*)&BmA[((ntb + j) * 16 + m) * 256 + kk * 32 + quad * 8];
            acc[j] = __builtin_amdgcn_mfma_f32_16x16x32_bf16(af, bf, acc[j], 0, 0, 0);
        }
    }
    long Mbase = (long)blockIdx.x * 32 + rows16;
#pragma unroll
    for (int j = 0; j < 2; ++j)
#pragma unroll
        for (int r = 0; r < 4; ++r)
            Y[(Mbase + quad * 4 + r) * 64 + (ntb + j) * 16 + m] = acc[j][r];
}

// A2: Z[(m*32+ky)*256 + bi] = sum_h Y[bi][h][ky] * e^{-2pi i kx h/256}.
// Grid 2048: block = bi*8+q, ky slice [q*4, q*4+4). 256 thr = 64 m x 4 h-chunks of 64.
__global__ void k_dft_h(const float2* __restrict__ Y, const float2* __restrict__ tw,
                        float2* __restrict__ Z) {
    __shared__ __align__(16) float2 Ys[256][4];   // [h][kk] 8 KB
    __shared__ float2 Lred[4 * 64 * 4];           // [sub][m][kk] 8 KB
    int t = threadIdx.x;
    int bi = blockIdx.x >> 3, ky0 = (blockIdx.x & 7) * 4;
    const float2* Yb = Y + (long)bi * 8192 + ky0;
    for (int j = t; j < 1024; j += BD) Ys[j >> 2][j & 3] = Yb[(j >> 2) * 32 + (j & 3)];
    int m = t & 63, sub = t >> 6;
    int kx = (m < 32) ? m : m + 192;
    float2 st = tw[kx];                          // step e^{i 2pi kx/256}
    float C = st.x, S = st.y;
    float2 s0 = tw[(kx * sub * 64) & 255];       // start phase for h0 = sub*64
    float cr = s0.x, ci = s0.y;
    float zr[4] = {}, zi[4] = {};
    __syncthreads();
    int h0 = sub * 64;
    for (int hh = 0; hh < 64; ++hh) {
        float4 ya = *(const float4*)&Ys[h0 + hh][0];   // broadcast
        float4 yb2 = *(const float4*)&Ys[h0 + hh][2];
        zr[0] = fmaf(ya.x, cr, fmaf(ya.y,  ci, zr[0]));
        zi[0] = fmaf(ya.y, cr, fmaf(-ya.x, ci, zi[0]));
        zr[1] = fmaf(ya.z, cr, fmaf(ya.w,  ci, zr[1]));
        zi[1] = fmaf(ya.w, cr, fmaf(-ya.z, ci, zi[1]));
        zr[2] = fmaf(yb2.x, cr, fmaf(yb2.y,  ci, zr[2]));
        zi[2] = fmaf(yb2.y, cr, fmaf(-yb2.x, ci, zi[2]));
        zr[3] = fmaf(yb2.z, cr, fmaf(yb2.w,  ci, zr[3]));
        zi[3] = fmaf(yb2.w, cr, fmaf(-yb2.z, ci, zi[3]));
        float nc = fmaf(cr, C, -ci * S);
        ci = fmaf(ci, C, cr * S);
        cr = nc;
    }
#pragma unroll
    for (int k = 0; k < 4; ++k) Lred[(sub * 64 + m) * 4 + k] = make_float2(zr[k], zi[k]);
    __syncthreads();
    int m2 = t & 63, k2 = t >> 6;
    float2 a0 = Lred[(0 * 64 + m2) * 4 + k2];
    float2 a1 = Lred[(1 * 64 + m2) * 4 + k2];
    float2 a2 = Lred[(2 * 64 + m2) * 4 + k2];
    float2 a3 = Lred[(3 * 64 + m2) * 4 + k2];
    Z[((long)m2 * 32 + ky0 + k2) * 256 + bi] =
        make_float2(a0.x + a1.x + a2.x + a3.x, a0.y + a1.y + a2.y + a3.y);
}

// B: Zmix[(b*32+o)*2048 + mk] = sum_i Z[mk*256 + b*32+i] * W[mk][i][o]
// Weights read directly (L2-resident 16 MB), scaled inline.
__global__ void k_mix(const float2* __restrict__ Z,
                      const float* __restrict__ w1r, const float* __restrict__ w1i,
                      const float* __restrict__ w2r, const float* __restrict__ w2i,
                      float2* __restrict__ Zmix) {
    __shared__ float2 Zs[256];
    __shared__ float2 Ws[1024];
    int t = threadIdx.x;
    int mk = blockIdx.x;                  // m*32+ky
    int m = mk >> 5, ky = mk & 31;
    Zs[t] = Z[(long)mk * 256 + t];        // coalesced
    const float* wr_src = (m < 32) ? w1r : w2r;
    const float* wi_src = (m < 32) ? w1i : w2i;
    int woff = (m & 31) * 32 + ky;
    float scale = (ky == 0 ? 1.0f : 2.0f) * (1.0f / 65536.0f);
    for (int j = t; j < 1024; j += BD)    // j = i*32+o, stride-4KB gather, L2-served
        Ws[j] = make_float2(wr_src[j * 1024 + woff] * scale, wi_src[j * 1024 + woff] * scale);
    __syncthreads();
    int b = t >> 5, o = t & 31;
    float ar = 0.f, ai = 0.f;
#pragma unroll
    for (int i = 0; i < 32; ++i) {
        float2 z = Zs[b * 32 + i];
        float2 w = Ws[i * 32 + o];
        ar = fmaf(z.x, w.x, fmaf(-z.y, w.y, ar));
        ai = fmaf(z.x, w.y, fmaf(z.y,  w.x, ai));
    }
    Zmix[(long)t * 2048 + mk] = make_float2(ar, ai);
}

// C1: G[bo][h][2ky+c] (bf16) = sum_m Zmix[bo*2048 + m*32+ky] * e^{+2pi i kx h/256}.
// Grid 2048: block = bo*8+q, ky slice of 4. Thread t = h.
__global__ void k_idft_h(const float2* __restrict__ Zmix, const float2* __restrict__ tw,
                         unsigned short* __restrict__ Gb) {
    __shared__ __align__(16) float2 Zs[64][4];    // [m][kk] 2 KB
    int t = threadIdx.x;
    int bo = blockIdx.x >> 3, ky0 = (blockIdx.x & 7) * 4;
    const float2* Zb = Zmix + (long)bo * 2048 + ky0;
    for (int j = t; j < 256; j += BD) Zs[j >> 2][j & 3] = Zb[(j >> 2) * 32 + (j & 3)];
    float2 st = tw[t];                  // step e^{i 2pi h/256}, h = t
    float C = st.x, S = st.y;
    __syncthreads();
    float gr[4] = {}, gi[4] = {};
    float cr = 1.f, ci = 0.f;
    for (int half = 0; half < 2; ++half) {
        if (half) { float2 s2 = tw[(224 * t) & 255]; cr = s2.x; ci = s2.y; }
        for (int mm = 0; mm < 32; ++mm) {
            int m = half * 32 + mm;
            float4 za = *(const float4*)&Zs[m][0];   // broadcast
            float4 zb2 = *(const float4*)&Zs[m][2];
            gr[0] = fmaf(za.x, cr, fmaf(-za.y, ci, gr[0]));
            gi[0] = fmaf(za.y, cr, fmaf( za.x, ci, gi[0]));
            gr[1] = fmaf(za.z, cr, fmaf(-za.w, ci, gr[1]));
            gi[1] = fmaf(za.w, cr, fmaf( za.z, ci, gi[1]));
            gr[2] = fmaf(zb2.x, cr, fmaf(-zb2.y, ci, gr[2]));
            gi[2] = fmaf(zb2.y, cr, fmaf( zb2.x, ci, gi[2]));
            gr[3] = fmaf(zb2.z, cr, fmaf(-zb2.w, ci, gr[3]));
            gi[3] = fmaf(zb2.w, cr, fmaf( zb2.z, ci, gi[3]));
            float nc = fmaf(cr, C, -ci * S);
            ci = fmaf(ci, C, cr * S);
            cr = nc;
        }
    }
    unsigned* Gp = (unsigned*)(Gb + (((long)bo * 256 + t) * 64 + ky0 * 2));
#pragma unroll
    for (int k = 0; k < 4; ++k)
        Gp[k] = (unsigned)f2bf(gr[k]) | ((unsigned)f2bf(gi[k]) << 16);
}

// C2 (MFMA): out[row][w] = bias + sum_k G[row][k] * BmC[w][k].  M-tile=64, N=256, K=64.
// B fragments straight from global BmC (32 KB, L1-resident).
__global__ void k_idft_w_mfma(const unsigned short* __restrict__ Gb,
                              const unsigned short* __restrict__ BmC,
                              const float* __restrict__ bias, float* __restrict__ out) {
    __shared__ unsigned short As[64 * 72];    // 64 rows x 64 bf16, k-stride 72
    int t = threadIdx.x;
    {   // stage A
        int r = t >> 2, c0 = (t & 3) * 16;
        const uint4* src = (const uint4*)(Gb + ((long)blockIdx.x * 64 + r) * 64 + c0);
        unsigned short* dst = &As[r * 72 + c0];
        *(uint4*)(dst) = src[0];
        *(uint4*)(dst + 8) = src[1];
    }
    __syncthreads();
    int wv = t >> 6, lane = t & 63;
    int m = lane & 15, quad = lane >> 4;
    f32x4 acc[16] = {};
    bf16x8 a0 = *(const bf16x8*)&As[(wv * 16 + m) * 72 + quad * 8];
    bf16x8 a1 = *(const bf16x8*)&As[(wv * 16 + m) * 72 + 32 + quad * 8];
#pragma unroll
    for (int nt = 0; nt < 16; ++nt) {
        bf16x8 b0 = *(const bf16x8*)&BmC[(nt * 16 + m) * 64 + quad * 8];
        bf16x8 b1 = *(const bf16x8*)&BmC[(nt * 16 + m) * 64 + 32 + quad * 8];
        acc[nt] = __builtin_amdgcn_mfma_f32_16x16x32_bf16(a0, b0, acc[nt], 0, 0, 0);
        acc[nt] = __builtin_amdgcn_mfma_f32_16x16x32_bf16(a1, b1, acc[nt], 0, 0, 0);
    }
    float bv = bias[(blockIdx.x >> 2) & 31];
    long rowbase = (long)blockIdx.x * 64 + wv * 16;
#pragma unroll
    for (int nt = 0; nt < 16; ++nt)
#pragma unroll
        for (int r = 0; r < 4; ++r)
            out[(rowbase + quad * 4 + r) * 256 + nt * 16 + m] = acc[nt][r] + bv;
}

extern "C" void kernel_launch(void* const* d_in, const int* in_sizes, int n_in,
                              void* d_out, int out_size, void* d_ws, size_t ws_size,
                              hipStream_t stream) {
    const float* x    = (const float*)d_in[0];
    const float* w1r  = (const float*)d_in[1];
    const float* w1i  = (const float*)d_in[2];
    const float* w2r  = (const float*)d_in[3];
    const float* w2i  = (const float*)d_in[4];
    const float* bias = (const float*)d_in[5];

    char* ws = (char*)d_ws;
    float2* tw             = (float2*)(ws);                          // 2 KB (slot 4 KB)
    unsigned short* BmA    = (unsigned short*)(ws + 4096);           // 32 KB
    unsigned short* BmC    = BmA + 64 * 256;                         // 32 KB
    float* Y               = (float*)(ws + 4096 + 65536);            // 16 MB
    float2* Z              = (float2*)((char*)Y + (16l << 20));      // 4 MB   [mk][bi]
    float2* Zmix           = (float2*)((char*)Z + (4l << 20));       // 4 MB   [bo][mk]
    unsigned short* Gb     = (unsigned short*)Y;    // alias: Y dead after k_dft_h
    float* out             = (float*)d_out;

    k_setup       <<<129, BD, 0, stream>>>(tw, BmA, BmC);
    k_dft_w_mfma  <<<2048, BD, 0, stream>>>(x, BmA, Y);
    k_dft_h       <<<2048, BD, 0, stream>>>((const float2*)Y, tw, Z);
    k_mix         <<<2048, BD, 0, stream>>>(Z, w1r, w1i, w2r, w2i, Zmix);
    k_idft_h      <<<2048, BD, 0, stream>>>(Zmix, tw, Gb);
    k_idft_w_mfma <<<1024, BD, 0, stream>>>(Gb, BmC, bias, out);
}